// Round 1
// baseline (156.566 us; speedup 1.0000x reference)
//
#include <hip/hip_runtime.h>

// Problem constants (match reference setup_inputs):
//   B=32, N=3072, F=256, P=3, S=N/P=1024
// out shape (B, S, F, 1) -> flat B*S*F floats.
constexpr int Bdim = 32;
constexpr int Ndim = 3072;
constexpr int Fdim = 256;
constexpr int Pdim = 3;
constexpr int Sdim = Ndim / Pdim;   // 1024
constexpr int WAVES_PER_BLOCK = 4;  // 256 threads

// One 64-lane wave per window (b, s). Lane i owns float4 at f = 4*i.
__global__ __launch_bounds__(256) void gap_kernel(
    const float* __restrict__ x,   // [B, N, F]
    const float* __restrict__ w,   // [F]
    float* __restrict__ out)       // [B, S, F]
{
    const int lane = threadIdx.x & 63;
    const int wave = threadIdx.x >> 6;
    const int win  = blockIdx.x * WAVES_PER_BLOCK + wave;   // 0 .. B*S-1
    const int b = win >> 10;          // S = 1024
    const int s = win & (Sdim - 1);

    const size_t row0 = ((size_t)b * Ndim + (size_t)s * Pdim) * Fdim + lane * 4;
    const float4 w4 = *(const float4*)(w + lane * 4);
    const float4 r0 = *(const float4*)(x + row0);
    const float4 r1 = *(const float4*)(x + row0 + Fdim);
    const float4 r2 = *(const float4*)(x + row0 + 2 * Fdim);

    float d0 = r0.x * w4.x + r0.y * w4.y + r0.z * w4.z + r0.w * w4.w;
    float d1 = r1.x * w4.x + r1.y * w4.y + r1.z * w4.z + r1.w * w4.w;
    float d2 = r2.x * w4.x + r2.y * w4.y + r2.z * w4.z + r2.w * w4.w;

    // Butterfly reduce across the 64-lane wave (all three dots together).
    #pragma unroll
    for (int off = 32; off >= 1; off >>= 1) {
        d0 += __shfl_xor(d0, off, 64);
        d1 += __shfl_xor(d1, off, 64);
        d2 += __shfl_xor(d2, off, 64);
    }

    // Softmax over the 3 scores (bias is uniform -> cancels in softmax).
    const float m  = fmaxf(d0, fmaxf(d1, d2));
    float e0 = __expf(d0 - m);
    float e1 = __expf(d1 - m);
    float e2 = __expf(d2 - m);
    const float inv = 1.0f / (e0 + e1 + e2);
    e0 *= inv; e1 *= inv; e2 *= inv;

    float4 o;
    o.x = r0.x * e0 + r1.x * e1 + r2.x * e2;
    o.y = r0.y * e0 + r1.y * e1 + r2.y * e2;
    o.z = r0.z * e0 + r1.z * e1 + r2.z * e2;
    o.w = r0.w * e0 + r1.w * e1 + r2.w * e2;

    *(float4*)(out + (size_t)win * Fdim + lane * 4) = o;
}

extern "C" void kernel_launch(void* const* d_in, const int* in_sizes, int n_in,
                              void* d_out, int out_size, void* d_ws, size_t ws_size,
                              hipStream_t stream) {
    const float* x = (const float*)d_in[0];   // [B, N, F] fp32
    const float* w = (const float*)d_in[1];   // [F] fp32
    // d_in[2] = W_bias — uniform additive constant, cancels in softmax.
    float* out = (float*)d_out;               // [B, S, F, 1] fp32

    const int n_windows = Bdim * Sdim;                    // 32768
    const int grid = n_windows / WAVES_PER_BLOCK;         // 8192
    gap_kernel<<<grid, WAVES_PER_BLOCK * 64, 0, stream>>>(x, w, out);
}

// Round 2
// 154.831 us; speedup vs baseline: 1.0112x; 1.0112x over previous
//
#include <hip/hip_runtime.h>

// Problem constants (match reference setup_inputs):
//   B=32, N=3072, F=256, P=3, S=N/P=1024
// out shape (B, S, F, 1) -> flat B*S*F floats.
constexpr int Bdim = 32;
constexpr int Ndim = 3072;
constexpr int Fdim = 256;
constexpr int Pdim = 3;
constexpr int Sdim = Ndim / Pdim;   // 1024
constexpr int WAVES_PER_BLOCK = 4;  // 256 threads

// Full 64-lane sum via DPP (VALU-only, no LDS pipe):
//   row_shr:1,2,4,8 -> inclusive prefix within each 16-lane row (lane15/31/47/63 = row sums)
//   row_bcast:15    -> lane31 += rowsum0 ; lane63 += rowsum2 (pre-op values)
//   row_bcast:31    -> lane63 = (rowsum2+rowsum3) + (rowsum0+rowsum1) = total
// then broadcast lane 63 to all lanes via readlane (SGPR).
__device__ __forceinline__ float wave_allsum(float v) {
    float t = v;
    int x;
    x = __builtin_amdgcn_update_dpp(0, __float_as_int(t), 0x111, 0xF, 0xF, true); // row_shr:1
    t += __int_as_float(x);
    x = __builtin_amdgcn_update_dpp(0, __float_as_int(t), 0x112, 0xF, 0xF, true); // row_shr:2
    t += __int_as_float(x);
    x = __builtin_amdgcn_update_dpp(0, __float_as_int(t), 0x114, 0xF, 0xF, true); // row_shr:4
    t += __int_as_float(x);
    x = __builtin_amdgcn_update_dpp(0, __float_as_int(t), 0x118, 0xF, 0xF, true); // row_shr:8
    t += __int_as_float(x);
    x = __builtin_amdgcn_update_dpp(0, __float_as_int(t), 0x142, 0xF, 0xF, true); // row_bcast:15
    t += __int_as_float(x);
    x = __builtin_amdgcn_update_dpp(0, __float_as_int(t), 0x143, 0xF, 0xF, true); // row_bcast:31
    t += __int_as_float(x);
    return __int_as_float(__builtin_amdgcn_readlane(__float_as_int(t), 63));
}

// One 64-lane wave per window (b, s). Lane i owns float4 at f = 4*i.
__global__ __launch_bounds__(256) void gap_kernel(
    const float* __restrict__ x,   // [B, N, F]
    const float* __restrict__ w,   // [F]
    float* __restrict__ out)       // [B, S, F]
{
    const int lane = threadIdx.x & 63;
    const int wave = threadIdx.x >> 6;
    const int win  = blockIdx.x * WAVES_PER_BLOCK + wave;   // 0 .. B*S-1

    const size_t row0 = (size_t)win * (Pdim * Fdim) + lane * 4;  // B*N*F flat; windows are contiguous
    const float4 w4 = *(const float4*)(w + lane * 4);
    const float4 r0 = *(const float4*)(x + row0);
    const float4 r1 = *(const float4*)(x + row0 + Fdim);
    const float4 r2 = *(const float4*)(x + row0 + 2 * Fdim);

    float p0 = r0.x * w4.x + r0.y * w4.y + r0.z * w4.z + r0.w * w4.w;
    float p1 = r1.x * w4.x + r1.y * w4.y + r1.z * w4.z + r1.w * w4.w;
    float p2 = r2.x * w4.x + r2.y * w4.y + r2.z * w4.z + r2.w * w4.w;

    // VALU-only cross-lane reduction (three independent chains, interleaved by scheduler).
    const float d0 = wave_allsum(p0);
    const float d1 = wave_allsum(p1);
    const float d2 = wave_allsum(p2);

    // Softmax over the 3 scores (bias is uniform -> cancels in softmax).
    const float m  = fmaxf(d0, fmaxf(d1, d2));
    float e0 = __expf(d0 - m);
    float e1 = __expf(d1 - m);
    float e2 = __expf(d2 - m);
    const float inv = 1.0f / (e0 + e1 + e2);
    e0 *= inv; e1 *= inv; e2 *= inv;

    float4 o;
    o.x = r0.x * e0 + r1.x * e1 + r2.x * e2;
    o.y = r0.y * e0 + r1.y * e1 + r2.y * e2;
    o.z = r0.z * e0 + r1.z * e1 + r2.z * e2;
    o.w = r0.w * e0 + r1.w * e1 + r2.w * e2;

    *(float4*)(out + (size_t)win * Fdim + lane * 4) = o;
}

extern "C" void kernel_launch(void* const* d_in, const int* in_sizes, int n_in,
                              void* d_out, int out_size, void* d_ws, size_t ws_size,
                              hipStream_t stream) {
    const float* x = (const float*)d_in[0];   // [B, N, F] fp32
    const float* w = (const float*)d_in[1];   // [F] fp32
    // d_in[2] = W_bias — uniform additive constant, cancels in softmax.
    float* out = (float*)d_out;               // [B, S, F, 1] fp32

    const int n_windows = Bdim * Sdim;                    // 32768
    const int grid = n_windows / WAVES_PER_BLOCK;         // 8192
    gap_kernel<<<grid, WAVES_PER_BLOCK * 64, 0, stream>>>(x, w, out);
}